// Round 3
// baseline (170.960 us; speedup 1.0000x reference)
//
#include <hip/hip_runtime.h>

typedef __attribute__((ext_vector_type(8))) __bf16 bf16x8;
typedef __attribute__((ext_vector_type(8))) unsigned short u16x8;
typedef __attribute__((ext_vector_type(4))) float f32x4;

#define LOG2E 1.4426950408889634f

// async global -> LDS, 16 bytes per lane (dest must be wave-uniform base + lane*16)
#define GLDS16(gp, lp)                                                \
  __builtin_amdgcn_global_load_lds(                                   \
      (const __attribute__((address_space(1))) void*)(gp),            \
      (__attribute__((address_space(3))) void*)(lp), 16, 0, 0)

__device__ __forceinline__ unsigned short f2b(float f) {
  return __builtin_bit_cast(unsigned short, (__bf16)f);
}
__device__ __forceinline__ float b2f(unsigned short h) {
  return __uint_as_float(((unsigned)h) << 16);
}

// -- 1) fused: xb = bf16(x)  AND  v[b,t,j,d] = sum_i x[b,t,i*64+d]*v_tmp[i*16+j]
__global__ __launch_bounds__(256) void k_xv(const float* __restrict__ x,
                                            const float* __restrict__ vt,
                                            unsigned short* __restrict__ xb,
                                            unsigned short* __restrict__ vb) {
  __shared__ float s_vt[256];
  s_vt[threadIdx.x] = vt[threadIdx.x];
  __syncthreads();
  int g = blockIdx.x * 256 + threadIdx.x;
  int bt = g >> 6, d = g & 63;
  const float* xp = x + (size_t)bt * 1024 + d;
  float xi[16];
#pragma unroll
  for (int i = 0; i < 16; ++i) xi[i] = xp[i * 64];
#pragma unroll
  for (int i = 0; i < 16; ++i) xb[(size_t)bt * 1024 + i * 64 + d] = f2b(xi[i]);
#pragma unroll
  for (int j = 0; j < 16; ++j) {
    float s = 0.f;
#pragma unroll
    for (int i = 0; i < 16; ++i) s += xi[i] * s_vt[i * 16 + j];
    vb[(size_t)bt * 1024 + j * 64 + d] = f2b(s);
  }
}

// ------- 2) W [1024][2048] fp32 -> Wt [2048][1024] bf16 (transposed) --------
__global__ __launch_bounds__(256) void k_trans_w(const float* __restrict__ W,
                                                 unsigned short* __restrict__ Wt) {
  __shared__ unsigned short tile[64][65];
  int n0 = blockIdx.x * 64;
  int k0 = blockIdx.y * 64;
  int tx = threadIdx.x & 63, ty = threadIdx.x >> 6;
#pragma unroll
  for (int r = 0; r < 16; ++r) {
    int kk = ty * 16 + r;
    tile[kk][tx] = f2b(W[(size_t)(k0 + kk) * 2048 + n0 + tx]);
  }
  __syncthreads();
#pragma unroll
  for (int r = 0; r < 16; ++r) {
    int nn = ty * 16 + r;
    Wt[(size_t)(n0 + nn) * 1024 + k0 + tx] = tile[tx][nn];
  }
}

// ---- 3) GEMM: qk[4096][2048] bf16 = xb[4096][1024] @ Wt[2048][1024]^T ------
__global__ __launch_bounds__(256) void k_gemm_qk(const unsigned short* __restrict__ A,
                                                 const unsigned short* __restrict__ Bt,
                                                 unsigned short* __restrict__ C) {
  __shared__ unsigned short As[128 * 32];
  __shared__ unsigned short Bs[128 * 32];
  const int K = 1024;
  int m0 = blockIdx.x * 128;
  int n0 = blockIdx.y * 128;
  int tid = threadIdx.x;
  int w = tid >> 6, lane = tid & 63;
  int lq = lane & 15, lk8 = (lane >> 4) * 8;
  int wr = (w >> 1) * 64, wc = (w & 1) * 64;
  f32x4 acc[4][4];
#pragma unroll
  for (int i = 0; i < 4; ++i)
#pragma unroll
    for (int j = 0; j < 4; ++j)
#pragma unroll
      for (int r = 0; r < 4; ++r) acc[i][j][r] = 0.f;

  for (int kk = 0; kk < K; kk += 32) {
    __syncthreads();
#pragma unroll
    for (int i = 0; i < 2; ++i) {
      int c = tid + 256 * i;
      int row = c >> 2, col = (c & 3) * 8;
      GLDS16(A + (size_t)(m0 + row) * K + kk + col, As + c * 8);
      GLDS16(Bt + (size_t)(n0 + row) * K + kk + col, Bs + c * 8);
    }
    __syncthreads();
    bf16x8 af[4], bf[4];
#pragma unroll
    for (int i = 0; i < 4; ++i) af[i] = *(const bf16x8*)(As + (wr + i * 16 + lq) * 32 + lk8);
#pragma unroll
    for (int j = 0; j < 4; ++j) bf[j] = *(const bf16x8*)(Bs + (wc + j * 16 + lq) * 32 + lk8);
#pragma unroll
    for (int i = 0; i < 4; ++i)
#pragma unroll
      for (int j = 0; j < 4; ++j)
        acc[i][j] = __builtin_amdgcn_mfma_f32_16x16x32_bf16(af[i], bf[j], acc[i][j], 0, 0, 0);
  }
#pragma unroll
  for (int i = 0; i < 4; ++i)
#pragma unroll
    for (int j = 0; j < 4; ++j)
#pragma unroll
      for (int r = 0; r < 4; ++r) {
        int m = m0 + wr + i * 16 + (lane >> 4) * 4 + r;
        int n = n0 + wc + j * 16 + lq;
        C[(size_t)m * 2048 + n] = f2b(acc[i][j][r]);
      }
}

// ------- 4) vb [2][2048][1024] -> Vt [2][1024][2048]  (t-major for PV) ------
__global__ __launch_bounds__(256) void k_vtrans(const unsigned short* __restrict__ vb,
                                                unsigned short* __restrict__ Vt) {
  __shared__ unsigned short tile[64][65];
  int t0 = blockIdx.x * 64;
  int c0 = blockIdx.y * 64;
  int b = blockIdx.z;
  int tx = threadIdx.x & 63, ty = threadIdx.x >> 6;
#pragma unroll
  for (int r = 0; r < 16; ++r) {
    int tt = ty * 16 + r;
    tile[tt][tx] = vb[((size_t)b * 2048 + t0 + tt) * 1024 + c0 + tx];
  }
  __syncthreads();
#pragma unroll
  for (int r = 0; r < 16; ++r) {
    int cc = ty * 16 + r;
    Vt[((size_t)b * 1024 + c0 + cc) * 2048 + t0 + tx] = tile[tx][cc];
  }
}

// ---------------- 5) causal flash attention with ALiBi ----------------------
// R12: DUAL-QT — each block processes its paired q-tiles qtA=j and qtB=31-j
// CONCURRENTLY in one kt sweep (union range 0..qtB) instead of two passes.
// Per staged K/V tile: 2 independent MFMA/softmax chains per wave (in-wave
// ILP ~2x, hiding the serial QK->softmax->Pbuf->PV latency at the 2-wave/SIMD
// grid-limited occupancy); kc/vf LDS fragments read ONCE feed both chains
// (per-chain LDS traffic ~halved); stage count 33 -> max(j,31-j)+1 (avg 24.4,
// -26% DMA+barriers). Work per block stays uniform (33 tile-computes).
// Keeps: R11 XCD-group swizzle (FETCH 121->12 MB verified), global_load_lds
// double buffer, fixed-shift softmax, ones-column l, XOR-swizzled Pbuf
// (8 slots: A=w, B=4+w so chains don't alias), all-u16 LDS typing.
__global__ __launch_bounds__(256) void k_flash(const unsigned short* __restrict__ qkb, // [2][2048][2048]
                                               const unsigned short* __restrict__ Vt,  // [2][1024][2048]
                                               unsigned short* __restrict__ y) {       // [2][2048][1024]
  __shared__ unsigned short Ks[2][2][64 * 32];   // [buf][half][kg][d32]
  __shared__ unsigned short Vs[2][2][64 * 32];   // [buf][half][d][t32]
  __shared__ unsigned short Pbuf[8][16 * 64];    // [chain slot][16 rows][64]
  // ---- XCD-group decode: 32 groups (hd,b), group g on xcd g&7 ----
  int id = blockIdx.x;
  int xcd = id & 7, s = id >> 3;
  int grp = xcd + 8 * (s >> 4);                  // 0..31
  int j = s & 15;
  int hd = grp & 15, b = grp >> 4;
  int tid = threadIdx.x;
  int w = tid >> 6, lane = tid & 63;
  int quad = lane >> 4, lq = lane & 15, lk8 = quad * 8;
  int rs = tid >> 2, cs = (tid & 3) * 8;         // staging: row / 8-elem chunk
  const size_t rowb = (size_t)b * 2048;
  const size_t vrow = ((size_t)b * 1024 + hd * 64 + rs) * 2048 + cs;
  const size_t krow = ((rowb + rs) << 11) + 1024 + hd * 64 + cs;

  float slope = exp2f(-0.5f * (float)(hd + 1));  // ALiBi, H=16 power-of-2
  const float c1 = 0.125f * LOG2E;               // 1/sqrt(64) * log2(e)
  const float c2 = slope * LOG2E;
  const float SHIFT = 16.0f;                     // fixed softmax shift (log2)

  bf16x8 ones;
#pragma unroll
  for (int i = 0; i < 8; ++i) ones[i] = (__bf16)1.0f;

  const int qtA = j, qtB = 31 - j;               // qtA < qtB always (j in 0..15)
  int qgA = qtA * 64 + w * 16 + lq;
  int qgB = qtB * 64 + w * 16 + lq;
  bf16x8 qfA0 = *(const bf16x8*)(qkb + ((rowb + qgA) << 11) + hd * 64 + lk8);
  bf16x8 qfA1 = *(const bf16x8*)(qkb + ((rowb + qgA) << 11) + hd * 64 + 32 + lk8);
  bf16x8 qfB0 = *(const bf16x8*)(qkb + ((rowb + qgB) << 11) + hd * 64 + lk8);
  bf16x8 qfB1 = *(const bf16x8*)(qkb + ((rowb + qgB) << 11) + hd * 64 + 32 + lk8);
  const int qbaseA = qtA * 64 + w * 16 + quad * 4;  // C-layout rows: + r
  const int qbaseB = qtB * 64 + w * 16 + quad * 4;

  // ALiBi decomposition: arg = S*c1 + colv[s4] + row[r],
  // colv[s4] = c2*(k0+s4*16+lq), row[r] = -c2*(qbase+r) - SHIFT
  float rowA_[4], rowB_[4];
#pragma unroll
  for (int r = 0; r < 4; ++r) {
    rowA_[r] = -c2 * (float)(qbaseA + r) - SHIFT;
    rowB_[r] = -c2 * (float)(qbaseB + r) - SHIFT;
  }

  // P read-back swizzle constants
  int g0 = ((quad >> 1) ^ (lq >> 2)) << 4;
  int g1 = ((2 | (quad >> 1)) ^ (lq >> 2)) << 4;
  int sub = (quad & 1) * 8;

  f32x4 oA[4], oB[4], o4A, o4B;
#pragma unroll
  for (int r = 0; r < 4; ++r) { o4A[r] = 0.f; o4B[r] = 0.f; }
#pragma unroll
  for (int jj = 0; jj < 4; ++jj)
#pragma unroll
    for (int r = 0; r < 4; ++r) { oA[jj][r] = 0.f; oB[jj][r] = 0.f; }

  // QK^T for one chain from shared K fragments
  auto qk2 = [&](bf16x8 q0v, bf16x8 q1v, bf16x8 (*kc)[2], f32x4* S) {
#pragma unroll
    for (int s4 = 0; s4 < 4; ++s4) {
      f32x4 a;
#pragma unroll
      for (int r = 0; r < 4; ++r) a[r] = 0.f;
      a = __builtin_amdgcn_mfma_f32_16x16x32_bf16(q0v, kc[s4][0], a, 0, 0, 0);
      a = __builtin_amdgcn_mfma_f32_16x16x32_bf16(q1v, kc[s4][1], a, 0, 0, 0);
      S[s4] = a;
    }
  };
  // softmax + C->A relayout through per-chain Pbuf slot
  auto chain = [&](const f32x4* S, const float* rw, const float* colv, bool diag,
                   int qb, int k0, int pslot, bf16x8& pf0, bf16x8& pf1) {
    float p[4][4];
#pragma unroll
    for (int s4 = 0; s4 < 4; ++s4)
#pragma unroll
      for (int r = 0; r < 4; ++r) {
        float v = S[s4][r] * c1 + (colv[s4] + rw[r]);
        if (diag) {
          int kg = k0 + s4 * 16 + lq;
          v = (kg <= qb + r) ? v : -1e30f;
        }
        p[s4][r] = exp2f(v);
      }
#pragma unroll
    for (int s4 = 0; s4 < 4; ++s4) {
      int cg = (s4 ^ quad) << 4;
#pragma unroll
      for (int r = 0; r < 4; ++r)
        Pbuf[pslot][(quad * 4 + r) * 64 + cg + lq] = f2b(p[s4][r]);
    }
    u16x8 t0 = *(const u16x8*)(&Pbuf[pslot][lq * 64 + g0 + sub]);
    u16x8 t1 = *(const u16x8*)(&Pbuf[pslot][lq * 64 + g1 + sub]);
    pf0 = __builtin_bit_cast(bf16x8, t0);
    pf1 = __builtin_bit_cast(bf16x8, t1);
  };

  // ---- prologue: DMA tile 0 into buffer 0 ----
  GLDS16(qkb + krow,      &Ks[0][0][rs * 32 + cs]);
  GLDS16(qkb + krow + 32, &Ks[0][1][rs * 32 + cs]);
  GLDS16(Vt + vrow,       &Vs[0][0][rs * 32 + cs]);
  GLDS16(Vt + vrow + 32,  &Vs[0][1][rs * 32 + cs]);
  __syncthreads();
  int cur = 0;

  // ---------------- phase 1: kt in [0, qtA] — both chains ----------------
#pragma unroll 1
  for (int kt = 0; kt <= qtA; ++kt) {
    int k0 = kt * 64;
    {   // prefetch kt+1 (always valid: kt <= qtA < qtB)
      size_t koff = (size_t)(k0 + 64);
      int nxt = cur ^ 1;
      GLDS16(qkb + krow + (koff << 11),      &Ks[nxt][0][rs * 32 + cs]);
      GLDS16(qkb + krow + (koff << 11) + 32, &Ks[nxt][1][rs * 32 + cs]);
      GLDS16(Vt + vrow + koff,               &Vs[nxt][0][rs * 32 + cs]);
      GLDS16(Vt + vrow + koff + 32,          &Vs[nxt][1][rs * 32 + cs]);
    }
    bf16x8 kc[4][2];
#pragma unroll
    for (int s4 = 0; s4 < 4; ++s4) {
      u16x8 t0 = *(const u16x8*)(&Ks[cur][0][(s4 * 16 + lq) * 32 + lk8]);
      u16x8 t1 = *(const u16x8*)(&Ks[cur][1][(s4 * 16 + lq) * 32 + lk8]);
      kc[s4][0] = __builtin_bit_cast(bf16x8, t0);
      kc[s4][1] = __builtin_bit_cast(bf16x8, t1);
    }
    f32x4 SA[4], SB[4];
    qk2(qfA0, qfA1, kc, SA);
    qk2(qfB0, qfB1, kc, SB);
    float colv[4];
#pragma unroll
    for (int s4 = 0; s4 < 4; ++s4) colv[s4] = c2 * (float)(k0 + s4 * 16 + lq);
    bf16x8 pfA0, pfA1, pfB0, pfB1;
    if (kt == qtA) chain(SA, rowA_, colv, true,  qbaseA, k0, w,     pfA0, pfA1);
    else           chain(SA, rowA_, colv, false, qbaseA, k0, w,     pfA0, pfA1);
    chain(SB, rowB_, colv, false, qbaseB, k0, 4 + w, pfB0, pfB1);
    // PV: shared V fragments feed both chains
#pragma unroll
    for (int jj = 0; jj < 4; ++jj) {
      u16x8 v0 = *(const u16x8*)(&Vs[cur][0][(jj * 16 + lq) * 32 + lk8]);
      u16x8 v1 = *(const u16x8*)(&Vs[cur][1][(jj * 16 + lq) * 32 + lk8]);
      bf16x8 vf0 = __builtin_bit_cast(bf16x8, v0);
      bf16x8 vf1 = __builtin_bit_cast(bf16x8, v1);
      oA[jj] = __builtin_amdgcn_mfma_f32_16x16x32_bf16(pfA0, vf0, oA[jj], 0, 0, 0);
      oA[jj] = __builtin_amdgcn_mfma_f32_16x16x32_bf16(pfA1, vf1, oA[jj], 0, 0, 0);
      oB[jj] = __builtin_amdgcn_mfma_f32_16x16x32_bf16(pfB0, vf0, oB[jj], 0, 0, 0);
      oB[jj] = __builtin_amdgcn_mfma_f32_16x16x32_bf16(pfB1, vf1, oB[jj], 0, 0, 0);
      if (jj == 0) {
        o4A = __builtin_amdgcn_mfma_f32_16x16x32_bf16(pfA0, ones, o4A, 0, 0, 0);
        o4A = __builtin_amdgcn_mfma_f32_16x16x32_bf16(pfA1, ones, o4A, 0, 0, 0);
        o4B = __builtin_amdgcn_mfma_f32_16x16x32_bf16(pfB0, ones, o4B, 0, 0, 0);
        o4B = __builtin_amdgcn_mfma_f32_16x16x32_bf16(pfB1, ones, o4B, 0, 0, 0);
      }
    }
    __syncthreads();               // next tile staged (vmcnt drained) + reads done
    cur ^= 1;
  }

  // ---------------- phase 2: kt in (qtA, qtB] — chain B only ----------------
#pragma unroll 1
  for (int kt = qtA + 1; kt <= qtB; ++kt) {
    int k0 = kt * 64;
    if (kt < qtB) {
      size_t koff = (size_t)(k0 + 64);
      int nxt = cur ^ 1;
      GLDS16(qkb + krow + (koff << 11),      &Ks[nxt][0][rs * 32 + cs]);
      GLDS16(qkb + krow + (koff << 11) + 32, &Ks[nxt][1][rs * 32 + cs]);
      GLDS16(Vt + vrow + koff,               &Vs[nxt][0][rs * 32 + cs]);
      GLDS16(Vt + vrow + koff + 32,          &Vs[nxt][1][rs * 32 + cs]);
    }
    bf16x8 kc[4][2];
#pragma unroll
    for (int s4 = 0; s4 < 4; ++s4) {
      u16x8 t0 = *(const u16x8*)(&Ks[cur][0][(s4 * 16 + lq) * 32 + lk8]);
      u16x8 t1 = *(const u16x8*)(&Ks[cur][1][(s4 * 16 + lq) * 32 + lk8]);
      kc[s4][0] = __builtin_bit_cast(bf16x8, t0);
      kc[s4][1] = __builtin_bit_cast(bf16x8, t1);
    }
    f32x4 SB[4];
    qk2(qfB0, qfB1, kc, SB);
    float colv[4];
#pragma unroll
    for (int s4 = 0; s4 < 4; ++s4) colv[s4] = c2 * (float)(k0 + s4 * 16 + lq);
    bf16x8 pfB0, pfB1;
    if (kt == qtB) chain(SB, rowB_, colv, true,  qbaseB, k0, 4 + w, pfB0, pfB1);
    else           chain(SB, rowB_, colv, false, qbaseB, k0, 4 + w, pfB0, pfB1);
#pragma unroll
    for (int jj = 0; jj < 4; ++jj) {
      u16x8 v0 = *(const u16x8*)(&Vs[cur][0][(jj * 16 + lq) * 32 + lk8]);
      u16x8 v1 = *(const u16x8*)(&Vs[cur][1][(jj * 16 + lq) * 32 + lk8]);
      bf16x8 vf0 = __builtin_bit_cast(bf16x8, v0);
      bf16x8 vf1 = __builtin_bit_cast(bf16x8, v1);
      oB[jj] = __builtin_amdgcn_mfma_f32_16x16x32_bf16(pfB0, vf0, oB[jj], 0, 0, 0);
      oB[jj] = __builtin_amdgcn_mfma_f32_16x16x32_bf16(pfB1, vf1, oB[jj], 0, 0, 0);
      if (jj == 0) {
        o4B = __builtin_amdgcn_mfma_f32_16x16x32_bf16(pfB0, ones, o4B, 0, 0, 0);
        o4B = __builtin_amdgcn_mfma_f32_16x16x32_bf16(pfB1, ones, o4B, 0, 0, 0);
      }
    }
    if (kt < qtB) {
      __syncthreads();
      cur ^= 1;
    }
  }

  // ---------------- epilogue: y = o / l for both q-tiles ----------------
#pragma unroll
  for (int r = 0; r < 4; ++r) {
    float invA = 1.0f / o4A[r];
    float invB = 1.0f / o4B[r];
    int qrA = qbaseA + r, qrB = qbaseB + r;
#pragma unroll
    for (int jj = 0; jj < 4; ++jj) {
      y[((rowb + qrA) << 10) + hd * 64 + jj * 16 + lq] = f2b(oA[jj][r] * invA);
      y[((rowb + qrB) << 10) + hd * 64 + jj * 16 + lq] = f2b(oB[jj][r] * invB);
    }
  }
}

// --- 6) out[b,t,i*64+d] = sum_j y[b,t,j*64+d] * proj_tmp[i*16+j]  (FP32 out) ---
__global__ __launch_bounds__(256) void k_proj(const unsigned short* __restrict__ yb,
                                              const float* __restrict__ pt,
                                              float* __restrict__ out) {
  __shared__ float s_pt[256];
  s_pt[threadIdx.x] = pt[threadIdx.x];
  __syncthreads();
  int g = blockIdx.x * 256 + threadIdx.x;
  int bt = g >> 6, d = g & 63;
  float yj[16];
#pragma unroll
  for (int j = 0; j < 16; ++j) yj[j] = b2f(yb[(size_t)bt * 1024 + j * 64 + d]);
#pragma unroll
  for (int i = 0; i < 16; ++i) {
    float s = 0.f;
#pragma unroll
    for (int j = 0; j < 16; ++j) s += yj[j] * s_pt[i * 16 + j];
    out[(size_t)bt * 1024 + i * 64 + d] = s;
  }
}

extern "C" void kernel_launch(void* const* d_in, const int* in_sizes, int n_in,
                              void* d_out, int out_size, void* d_ws, size_t ws_size,
                              hipStream_t stream) {
  const float* x  = (const float*)d_in[0];   // [2][2048][1024] fp32
  const float* W  = (const float*)d_in[1];   // [1024][2048] fp32
  const float* vt = (const float*)d_in[2];   // [16][16] fp32
  const float* pt = (const float*)d_in[3];   // [16][16] fp32
  float* out = (float*)d_out;                // fp32 out

  char* ws = (char*)d_ws;
  unsigned short* xb  = (unsigned short*)(ws);                 //  8 MiB, reused as y
  unsigned short* Wt  = (unsigned short*)(ws + (8u  << 20));   //  4 MiB
  unsigned short* qkb = (unsigned short*)(ws + (12u << 20));   // 16 MiB
  unsigned short* vb  = (unsigned short*)(ws + (28u << 20));   //  8 MiB
  unsigned short* Vtr = (unsigned short*)(ws + (36u << 20));   //  8 MiB
  unsigned short* yb  = xb;  // xb dead after GEMM; flash writes y there

  k_xv     <<<1024, 256, 0, stream>>>(x, vt, xb, vb);
  k_trans_w<<<dim3(32, 16), 256, 0, stream>>>(W, Wt);
  k_gemm_qk<<<dim3(32, 16), 256, 0, stream>>>(xb, Wt, qkb);
  k_vtrans <<<dim3(32, 16, 2), 256, 0, stream>>>(vb, Vtr);
  k_flash  <<<512, 256, 0, stream>>>(qkb, Vtr, yb);
  k_proj   <<<1024, 256, 0, stream>>>(yb, pt, out);
}

// Round 4
// 164.781 us; speedup vs baseline: 1.0375x; 1.0375x over previous
//
#include <hip/hip_runtime.h>

typedef __attribute__((ext_vector_type(8))) __bf16 bf16x8;
typedef __attribute__((ext_vector_type(8))) unsigned short u16x8;
typedef __attribute__((ext_vector_type(4))) float f32x4;

#define LOG2E 1.4426950408889634f

// async global -> LDS, 16 bytes per lane (dest must be wave-uniform base + lane*16)
#define GLDS16(gp, lp)                                                \
  __builtin_amdgcn_global_load_lds(                                   \
      (const __attribute__((address_space(1))) void*)(gp),            \
      (__attribute__((address_space(3))) void*)(lp), 16, 0, 0)

__device__ __forceinline__ unsigned short f2b(float f) {
  return __builtin_bit_cast(unsigned short, (__bf16)f);
}
__device__ __forceinline__ float b2f(unsigned short h) {
  return __uint_as_float(((unsigned)h) << 16);
}

// -- 1) fused: xb = bf16(x)  AND  v[b,t,j,d] = sum_i x[b,t,i*64+d]*v_tmp[i*16+j]
__global__ __launch_bounds__(256) void k_xv(const float* __restrict__ x,
                                            const float* __restrict__ vt,
                                            unsigned short* __restrict__ xb,
                                            unsigned short* __restrict__ vb) {
  __shared__ float s_vt[256];
  s_vt[threadIdx.x] = vt[threadIdx.x];
  __syncthreads();
  int g = blockIdx.x * 256 + threadIdx.x;
  int bt = g >> 6, d = g & 63;
  const float* xp = x + (size_t)bt * 1024 + d;
  float xi[16];
#pragma unroll
  for (int i = 0; i < 16; ++i) xi[i] = xp[i * 64];
#pragma unroll
  for (int i = 0; i < 16; ++i) xb[(size_t)bt * 1024 + i * 64 + d] = f2b(xi[i]);
#pragma unroll
  for (int j = 0; j < 16; ++j) {
    float s = 0.f;
#pragma unroll
    for (int i = 0; i < 16; ++i) s += xi[i] * s_vt[i * 16 + j];
    vb[(size_t)bt * 1024 + j * 64 + d] = f2b(s);
  }
}

// ------- 2) W [1024][2048] fp32 -> Wt [2048][1024] bf16 (transposed) --------
__global__ __launch_bounds__(256) void k_trans_w(const float* __restrict__ W,
                                                 unsigned short* __restrict__ Wt) {
  __shared__ unsigned short tile[64][65];
  int n0 = blockIdx.x * 64;
  int k0 = blockIdx.y * 64;
  int tx = threadIdx.x & 63, ty = threadIdx.x >> 6;
#pragma unroll
  for (int r = 0; r < 16; ++r) {
    int kk = ty * 16 + r;
    tile[kk][tx] = f2b(W[(size_t)(k0 + kk) * 2048 + n0 + tx]);
  }
  __syncthreads();
#pragma unroll
  for (int r = 0; r < 16; ++r) {
    int nn = ty * 16 + r;
    Wt[(size_t)(n0 + nn) * 1024 + k0 + tx] = tile[tx][nn];
  }
}

// ---- 3) GEMM: qk[4096][2048] bf16 = xb[4096][1024] @ Wt[2048][1024]^T ------
__global__ __launch_bounds__(256) void k_gemm_qk(const unsigned short* __restrict__ A,
                                                 const unsigned short* __restrict__ Bt,
                                                 unsigned short* __restrict__ C) {
  __shared__ unsigned short As[128 * 32];
  __shared__ unsigned short Bs[128 * 32];
  const int K = 1024;
  int m0 = blockIdx.x * 128;
  int n0 = blockIdx.y * 128;
  int tid = threadIdx.x;
  int w = tid >> 6, lane = tid & 63;
  int lq = lane & 15, lk8 = (lane >> 4) * 8;
  int wr = (w >> 1) * 64, wc = (w & 1) * 64;
  f32x4 acc[4][4];
#pragma unroll
  for (int i = 0; i < 4; ++i)
#pragma unroll
    for (int j = 0; j < 4; ++j)
#pragma unroll
      for (int r = 0; r < 4; ++r) acc[i][j][r] = 0.f;

  for (int kk = 0; kk < K; kk += 32) {
    __syncthreads();
#pragma unroll
    for (int i = 0; i < 2; ++i) {
      int c = tid + 256 * i;
      int row = c >> 2, col = (c & 3) * 8;
      GLDS16(A + (size_t)(m0 + row) * K + kk + col, As + c * 8);
      GLDS16(Bt + (size_t)(n0 + row) * K + kk + col, Bs + c * 8);
    }
    __syncthreads();
    bf16x8 af[4], bf[4];
#pragma unroll
    for (int i = 0; i < 4; ++i) af[i] = *(const bf16x8*)(As + (wr + i * 16 + lq) * 32 + lk8);
#pragma unroll
    for (int j = 0; j < 4; ++j) bf[j] = *(const bf16x8*)(Bs + (wc + j * 16 + lq) * 32 + lk8);
#pragma unroll
    for (int i = 0; i < 4; ++i)
#pragma unroll
      for (int j = 0; j < 4; ++j)
        acc[i][j] = __builtin_amdgcn_mfma_f32_16x16x32_bf16(af[i], bf[j], acc[i][j], 0, 0, 0);
  }
#pragma unroll
  for (int i = 0; i < 4; ++i)
#pragma unroll
    for (int j = 0; j < 4; ++j)
#pragma unroll
      for (int r = 0; r < 4; ++r) {
        int m = m0 + wr + i * 16 + (lane >> 4) * 4 + r;
        int n = n0 + wc + j * 16 + lq;
        C[(size_t)m * 2048 + n] = f2b(acc[i][j][r]);
      }
}

// ------- 4) vb [2][2048][1024] -> Vt [2][1024][2048]  (t-major for PV) ------
__global__ __launch_bounds__(256) void k_vtrans(const unsigned short* __restrict__ vb,
                                                unsigned short* __restrict__ Vt) {
  __shared__ unsigned short tile[64][65];
  int t0 = blockIdx.x * 64;
  int c0 = blockIdx.y * 64;
  int b = blockIdx.z;
  int tx = threadIdx.x & 63, ty = threadIdx.x >> 6;
#pragma unroll
  for (int r = 0; r < 16; ++r) {
    int tt = ty * 16 + r;
    tile[tt][tx] = vb[((size_t)b * 2048 + t0 + tt) * 1024 + c0 + tx];
  }
  __syncthreads();
#pragma unroll
  for (int r = 0; r < 16; ++r) {
    int cc = ty * 16 + r;
    Vt[((size_t)b * 1024 + c0 + cc) * 2048 + t0 + tx] = tile[tx][cc];
  }
}

// ---------------- 5) causal flash attention with ALiBi ----------------------
// R13: ONE q-tile per block, grid 1024 (= 4 blocks/CU avg, doubling resident
// waves/SIMD 2 -> 4). R12's dual-chain ILP was neutral (lgkmcnt counting
// fences serialized the chains); the missing resource is WAVES, not in-wave
// ILP (all pipes <45% at 2 waves/SIMD). Load balance by DESCENDING-size
// dispatch: qt = 31 - rank, so 32-tile blocks launch first and 1-tile blocks
// fill the scheduler tail. Keeps: R11 XCD-group decode (4 (hd,b) groups per
// XCD, FETCH 12 MB verified), global_load_lds double buffer, hoisted ALiBi,
// fixed-shift softmax, ones-column l, XOR-swizzled Pbuf, all-u16 LDS typing.
__global__ __launch_bounds__(256) void k_flash(const unsigned short* __restrict__ qkb, // [2][2048][2048]
                                               const unsigned short* __restrict__ Vt,  // [2][1024][2048]
                                               unsigned short* __restrict__ y) {       // [2][2048][1024]
  __shared__ unsigned short Ks[2][2][64 * 32];   // [buf][half][kg][d32]
  __shared__ unsigned short Vs[2][2][64 * 32];   // [buf][half][d][t32]
  __shared__ unsigned short Pbuf[4][16 * 64];
  // ---- decode: xcd = id&7; s = id>>3; group-local = s&3; qt = 31-(s>>2) ----
  int id = blockIdx.x;
  int xcd = id & 7, s = id >> 3;
  int grp = xcd + 8 * (s & 3);                   // 32 (hd,b) groups, 4 per XCD
  int qt = 31 - (s >> 2);                        // big blocks dispatched first
  int hd = grp & 15, b = grp >> 4;
  int tid = threadIdx.x;
  int w = tid >> 6, lane = tid & 63;
  int quad = lane >> 4, lq = lane & 15, lk8 = quad * 8;
  int rs = tid >> 2, cs = (tid & 3) * 8;         // staging: row / 8-elem chunk
  const size_t rowb = (size_t)b * 2048;
  const size_t vrow = ((size_t)b * 1024 + hd * 64 + rs) * 2048 + cs;
  const size_t krow = ((rowb + rs) << 11) + 1024 + hd * 64 + cs;

  float slope = exp2f(-0.5f * (float)(hd + 1));  // ALiBi, H=16 power-of-2
  const float c1 = 0.125f * LOG2E;               // 1/sqrt(64) * log2(e)
  const float c2 = slope * LOG2E;
  const float SHIFT = 16.0f;                     // fixed softmax shift (log2)

  bf16x8 ones;
#pragma unroll
  for (int i = 0; i < 8; ++i) ones[i] = (__bf16)1.0f;

  int q0 = qt * 64;
  int qg = q0 + w * 16 + lq;                     // A-frag row (m = lane&15)
  bf16x8 qf0 = *(const bf16x8*)(qkb + ((rowb + qg) << 11) + hd * 64 + lk8);
  bf16x8 qf1 = *(const bf16x8*)(qkb + ((rowb + qg) << 11) + hd * 64 + 32 + lk8);
  int qrow_base = q0 + w * 16 + quad * 4;        // C-layout rows: + r

  // hoisted ALiBi bias: score += base_b[s4][r] + c2*k0
  float base_b[4][4];
#pragma unroll
  for (int s4 = 0; s4 < 4; ++s4)
#pragma unroll
    for (int r = 0; r < 4; ++r)
      base_b[s4][r] = c2 * (float)(s4 * 16 + lq - qrow_base - r) - SHIFT;

  f32x4 o[4], o4;
#pragma unroll
  for (int r = 0; r < 4; ++r) o4[r] = 0.f;
#pragma unroll
  for (int jj = 0; jj < 4; ++jj)
#pragma unroll
    for (int r = 0; r < 4; ++r) o[jj][r] = 0.f;

  // ---- prologue: DMA tile 0 into buffer 0 ----
  GLDS16(qkb + krow,      &Ks[0][0][rs * 32 + cs]);
  GLDS16(qkb + krow + 32, &Ks[0][1][rs * 32 + cs]);
  GLDS16(Vt + vrow,       &Vs[0][0][rs * 32 + cs]);
  GLDS16(Vt + vrow + 32,  &Vs[0][1][rs * 32 + cs]);
  __syncthreads();                               // vmcnt(0) drain: tile 0 ready
  int cur = 0;

#pragma unroll 1
  for (int kt = 0; kt <= qt; ++kt) {
    int k0 = kt * 64;
    // DMA tile kt+1 into the other buffer (in flight across this tile)
    if (kt < qt) {
      size_t koff = (size_t)(k0 + 64);
      int nxt = cur ^ 1;
      GLDS16(qkb + krow + (koff << 11),      &Ks[nxt][0][rs * 32 + cs]);
      GLDS16(qkb + krow + (koff << 11) + 32, &Ks[nxt][1][rs * 32 + cs]);
      GLDS16(Vt + vrow + koff,               &Vs[nxt][0][rs * 32 + cs]);
      GLDS16(Vt + vrow + koff + 32,          &Vs[nxt][1][rs * 32 + cs]);
    }
    // K fragments from LDS
    bf16x8 kc[4][2];
#pragma unroll
    for (int s4 = 0; s4 < 4; ++s4) {
      u16x8 t0 = *(const u16x8*)(&Ks[cur][0][(s4 * 16 + lq) * 32 + lk8]);
      u16x8 t1 = *(const u16x8*)(&Ks[cur][1][(s4 * 16 + lq) * 32 + lk8]);
      kc[s4][0] = __builtin_bit_cast(bf16x8, t0);
      kc[s4][1] = __builtin_bit_cast(bf16x8, t1);
    }
    // QK^T
    f32x4 S[4];
#pragma unroll
    for (int s4 = 0; s4 < 4; ++s4) {
      f32x4 a;
#pragma unroll
      for (int r = 0; r < 4; ++r) a[r] = 0.f;
      a = __builtin_amdgcn_mfma_f32_16x16x32_bf16(qf0, kc[s4][0], a, 0, 0, 0);
      a = __builtin_amdgcn_mfma_f32_16x16x32_bf16(qf1, kc[s4][1], a, 0, 0, 0);
      S[s4] = a;
    }
    // p = exp2(score - SHIFT); masked cols -> 0
    float bk = c2 * (float)k0;
    float p[4][4];
    if (kt == qt) {
#pragma unroll
      for (int s4 = 0; s4 < 4; ++s4) {
        int kg = k0 + s4 * 16 + lq;
#pragma unroll
        for (int r = 0; r < 4; ++r) {
          int qr = qrow_base + r;
          float v = S[s4][r] * c1 + (base_b[s4][r] + bk);
          v = (kg <= qr) ? v : -1e30f;
          p[s4][r] = exp2f(v);
        }
      }
    } else {
#pragma unroll
      for (int s4 = 0; s4 < 4; ++s4) {
#pragma unroll
        for (int r = 0; r < 4; ++r) {
          float v = S[s4][r] * c1 + (base_b[s4][r] + bk);
          p[s4][r] = exp2f(v);
        }
      }
    }
    // P: C-layout -> LDS (XOR-swizzled) -> A-layout (per-wave, no barrier)
#pragma unroll
    for (int s4 = 0; s4 < 4; ++s4) {
      int cg = (s4 ^ quad) << 4;
#pragma unroll
      for (int r = 0; r < 4; ++r)
        Pbuf[w][(quad * 4 + r) * 64 + cg + lq] = f2b(p[s4][r]);
    }
    int g0 = ((quad >> 1) ^ (lq >> 2)) << 4;
    int g1 = ((2 | (quad >> 1)) ^ (lq >> 2)) << 4;
    int sub = (quad & 1) * 8;
    u16x8 t0 = *(const u16x8*)(&Pbuf[w][lq * 64 + g0 + sub]);
    u16x8 t1 = *(const u16x8*)(&Pbuf[w][lq * 64 + g1 + sub]);
    bf16x8 pf0 = __builtin_bit_cast(bf16x8, t0);
    bf16x8 pf1 = __builtin_bit_cast(bf16x8, t1);
    // V fragments from LDS, then PV + ones-column
#pragma unroll
    for (int jj = 0; jj < 4; ++jj) {
      u16x8 v0 = *(const u16x8*)(&Vs[cur][0][(jj * 16 + lq) * 32 + lk8]);
      u16x8 v1 = *(const u16x8*)(&Vs[cur][1][(jj * 16 + lq) * 32 + lk8]);
      bf16x8 vf0 = __builtin_bit_cast(bf16x8, v0);
      bf16x8 vf1 = __builtin_bit_cast(bf16x8, v1);
      o[jj] = __builtin_amdgcn_mfma_f32_16x16x32_bf16(pf0, vf0, o[jj], 0, 0, 0);
      o[jj] = __builtin_amdgcn_mfma_f32_16x16x32_bf16(pf1, vf1, o[jj], 0, 0, 0);
      if (jj == 0) {
        o4 = __builtin_amdgcn_mfma_f32_16x16x32_bf16(pf0, ones, o4, 0, 0, 0);
        o4 = __builtin_amdgcn_mfma_f32_16x16x32_bf16(pf1, ones, o4, 0, 0, 0);
      }
    }
    // switch buffers; DMA for tile kt+1 drains inside __syncthreads()
    if (kt < qt) {
      __syncthreads();
      cur ^= 1;
    }
  }
#pragma unroll
  for (int r = 0; r < 4; ++r) {
    float inv = 1.0f / o4[r];       // l (all cols of ones-acc equal)
    int qr = qrow_base + r;
#pragma unroll
    for (int jj = 0; jj < 4; ++jj)
      y[((rowb + qr) << 10) + hd * 64 + jj * 16 + lq] = f2b(o[jj][r] * inv);
  }
}

// --- 6) out[b,t,i*64+d] = sum_j y[b,t,j*64+d] * proj_tmp[i*16+j]  (FP32 out) ---
__global__ __launch_bounds__(256) void k_proj(const unsigned short* __restrict__ yb,
                                              const float* __restrict__ pt,
                                              float* __restrict__ out) {
  __shared__ float s_pt[256];
  s_pt[threadIdx.x] = pt[threadIdx.x];
  __syncthreads();
  int g = blockIdx.x * 256 + threadIdx.x;
  int bt = g >> 6, d = g & 63;
  float yj[16];
#pragma unroll
  for (int j = 0; j < 16; ++j) yj[j] = b2f(yb[(size_t)bt * 1024 + j * 64 + d]);
#pragma unroll
  for (int i = 0; i < 16; ++i) {
    float s = 0.f;
#pragma unroll
    for (int j = 0; j < 16; ++j) s += yj[j] * s_pt[i * 16 + j];
    out[(size_t)bt * 1024 + i * 64 + d] = s;
  }
}

extern "C" void kernel_launch(void* const* d_in, const int* in_sizes, int n_in,
                              void* d_out, int out_size, void* d_ws, size_t ws_size,
                              hipStream_t stream) {
  const float* x  = (const float*)d_in[0];   // [2][2048][1024] fp32
  const float* W  = (const float*)d_in[1];   // [1024][2048] fp32
  const float* vt = (const float*)d_in[2];   // [16][16] fp32
  const float* pt = (const float*)d_in[3];   // [16][16] fp32
  float* out = (float*)d_out;                // fp32 out

  char* ws = (char*)d_ws;
  unsigned short* xb  = (unsigned short*)(ws);                 //  8 MiB, reused as y
  unsigned short* Wt  = (unsigned short*)(ws + (8u  << 20));   //  4 MiB
  unsigned short* qkb = (unsigned short*)(ws + (12u << 20));   // 16 MiB
  unsigned short* vb  = (unsigned short*)(ws + (28u << 20));   //  8 MiB
  unsigned short* Vtr = (unsigned short*)(ws + (36u << 20));   //  8 MiB
  unsigned short* yb  = xb;  // xb dead after GEMM; flash writes y there

  k_xv     <<<1024, 256, 0, stream>>>(x, vt, xb, vb);
  k_trans_w<<<dim3(32, 16), 256, 0, stream>>>(W, Wt);
  k_gemm_qk<<<dim3(32, 16), 256, 0, stream>>>(xb, Wt, qkb);
  k_vtrans <<<dim3(32, 16, 2), 256, 0, stream>>>(vb, Vtr);
  k_flash  <<<1024, 256, 0, stream>>>(qkb, Vtr, yb);
  k_proj   <<<1024, 256, 0, stream>>>(yb, pt, out);
}

// Round 5
// 153.345 us; speedup vs baseline: 1.1149x; 1.0746x over previous
//
#include <hip/hip_runtime.h>

typedef __attribute__((ext_vector_type(8))) __bf16 bf16x8;
typedef __attribute__((ext_vector_type(8))) unsigned short u16x8;
typedef __attribute__((ext_vector_type(4))) float f32x4;
typedef __attribute__((ext_vector_type(4))) unsigned int u32x4;

#define LOG2E 1.4426950408889634f

// async global -> LDS, 16 bytes per lane (dest must be wave-uniform base + lane*16)
#define GLDS16(gp, lp)                                                \
  __builtin_amdgcn_global_load_lds(                                   \
      (const __attribute__((address_space(1))) void*)(gp),            \
      (__attribute__((address_space(3))) void*)(lp), 16, 0, 0)

__device__ __forceinline__ unsigned short f2b(float f) {
  return __builtin_bit_cast(unsigned short, (__bf16)f);
}
__device__ __forceinline__ float b2f(unsigned short h) {
  return __uint_as_float(((unsigned)h) << 16);
}
// v_cvt_pk_bf16_f32: lo16 = bf16(a), hi16 = bf16(b)   (no builtin on gfx950)
__device__ __forceinline__ unsigned cvt_pk(float a, float b) {
  unsigned r;
  asm("v_cvt_pk_bf16_f32 %0, %1, %2" : "=v"(r) : "v"(a), "v"(b));
  return r;
}
// gfx950: a' = [a01|b01], b' = [a23|b23]  (swap a.hi32lanes <-> b.lo32lanes)
__device__ __forceinline__ void swap32(unsigned& a, unsigned& b) {
  asm("v_permlane32_swap_b32 %0, %1" : "+v"(a), "+v"(b));
}
// gfx950: a' = [aq0,bq0,aq2,bq2], b' = [aq1,bq1,aq3,bq3]
__device__ __forceinline__ void swap16(unsigned& a, unsigned& b) {
  asm("v_permlane16_swap_b32 %0, %1" : "+v"(a), "+v"(b));
}

// -- 1) merged launch: [0,1024) xv: xb=bf16(x), v=x@v_tmp; [1024,1536) W transpose
__global__ __launch_bounds__(256) void k_pre(const float* __restrict__ x,
                                             const float* __restrict__ vt,
                                             const float* __restrict__ W,
                                             unsigned short* __restrict__ xb,
                                             unsigned short* __restrict__ vb,
                                             unsigned short* __restrict__ Wt) {
  if (blockIdx.x < 1024) {
    __shared__ float s_vt[256];
    s_vt[threadIdx.x] = vt[threadIdx.x];
    __syncthreads();
    int g = blockIdx.x * 256 + threadIdx.x;
    int bt = g >> 6, d = g & 63;
    const float* xp = x + (size_t)bt * 1024 + d;
    float xi[16];
#pragma unroll
    for (int i = 0; i < 16; ++i) xi[i] = xp[i * 64];
#pragma unroll
    for (int i = 0; i < 16; ++i) xb[(size_t)bt * 1024 + i * 64 + d] = f2b(xi[i]);
#pragma unroll
    for (int j = 0; j < 16; ++j) {
      float s = 0.f;
#pragma unroll
      for (int i = 0; i < 16; ++i) s += xi[i] * s_vt[i * 16 + j];
      vb[(size_t)bt * 1024 + j * 64 + d] = f2b(s);
    }
  } else {
    __shared__ unsigned short tile[64][65];
    int id2 = blockIdx.x - 1024;
    int n0 = (id2 & 31) * 64;
    int k0 = (id2 >> 5) * 64;
    int tx = threadIdx.x & 63, ty = threadIdx.x >> 6;
#pragma unroll
    for (int r = 0; r < 16; ++r) {
      int kk = ty * 16 + r;
      tile[kk][tx] = f2b(W[(size_t)(k0 + kk) * 2048 + n0 + tx]);
    }
    __syncthreads();
#pragma unroll
    for (int r = 0; r < 16; ++r) {
      int nn = ty * 16 + r;
      Wt[(size_t)(n0 + nn) * 1024 + k0 + tx] = tile[tx][nn];
    }
  }
}

// -- 2) merged launch: [0,512) GEMM qk = xb @ Wt^T (m97 DMA pattern);
//                      [512,1536) vb -> Vt transpose (t-major for PV)
__global__ __launch_bounds__(256) void k_mid(const unsigned short* __restrict__ A,
                                             const unsigned short* __restrict__ Bt,
                                             unsigned short* __restrict__ C,
                                             const unsigned short* __restrict__ vb,
                                             unsigned short* __restrict__ Vt) {
  if (blockIdx.x < 512) {
    __shared__ unsigned short As[128 * 32];
    __shared__ unsigned short Bs[128 * 32];
    const int K = 1024;
    int m0 = (blockIdx.x & 31) * 128;
    int n0 = (blockIdx.x >> 5) * 128;
    int tid = threadIdx.x;
    int w = tid >> 6, lane = tid & 63;
    int lq = lane & 15, lk8 = (lane >> 4) * 8;
    int wr = (w >> 1) * 64, wc = (w & 1) * 64;
    f32x4 acc[4][4];
#pragma unroll
    for (int i = 0; i < 4; ++i)
#pragma unroll
      for (int j = 0; j < 4; ++j)
#pragma unroll
        for (int r = 0; r < 4; ++r) acc[i][j][r] = 0.f;

    for (int kk = 0; kk < K; kk += 32) {
      __syncthreads();
#pragma unroll
      for (int i = 0; i < 2; ++i) {
        int c = tid + 256 * i;
        int row = c >> 2, col = (c & 3) * 8;
        GLDS16(A + (size_t)(m0 + row) * K + kk + col, As + c * 8);
        GLDS16(Bt + (size_t)(n0 + row) * K + kk + col, Bs + c * 8);
      }
      __syncthreads();
      bf16x8 af[4], bf[4];
#pragma unroll
      for (int i = 0; i < 4; ++i) af[i] = *(const bf16x8*)(As + (wr + i * 16 + lq) * 32 + lk8);
#pragma unroll
      for (int j = 0; j < 4; ++j) bf[j] = *(const bf16x8*)(Bs + (wc + j * 16 + lq) * 32 + lk8);
#pragma unroll
      for (int i = 0; i < 4; ++i)
#pragma unroll
        for (int j = 0; j < 4; ++j)
          acc[i][j] = __builtin_amdgcn_mfma_f32_16x16x32_bf16(af[i], bf[j], acc[i][j], 0, 0, 0);
    }
#pragma unroll
    for (int i = 0; i < 4; ++i)
#pragma unroll
      for (int j = 0; j < 4; ++j)
#pragma unroll
        for (int r = 0; r < 4; ++r) {
          int m = m0 + wr + i * 16 + (lane >> 4) * 4 + r;
          int n = n0 + wc + j * 16 + lq;
          C[(size_t)m * 2048 + n] = f2b(acc[i][j][r]);
        }
  } else {
    __shared__ unsigned short tile[64][65];
    int id2 = blockIdx.x - 512;
    int t0 = (id2 & 31) * 64;
    int c0 = ((id2 >> 5) & 15) * 64;
    int b = id2 >> 9;
    int tx = threadIdx.x & 63, ty = threadIdx.x >> 6;
#pragma unroll
    for (int r = 0; r < 16; ++r) {
      int tt = ty * 16 + r;
      tile[tt][tx] = vb[((size_t)b * 2048 + t0 + tt) * 1024 + c0 + tx];
    }
    __syncthreads();
#pragma unroll
    for (int r = 0; r < 16; ++r) {
      int cc = ty * 16 + r;
      Vt[((size_t)b * 1024 + c0 + cc) * 2048 + t0 + tx] = tile[tx][cc];
    }
  }
}

// ---------------- 3) causal flash attention with ALiBi ----------------------
// R14: k_flash was LDS-pipe-bound (~80% occupied; wave-count-insensitive per
// R12/R13). Two structural cuts:
//  (a) SWAPPED QK^T: S^T = mfma(K,Q) (same reg layouts, swapped operands) ->
//      q = lane&15, k = quad*4+r. P relayout for PV done IN REGISTERS:
//      8 cvt_pk + 8 v_permlane{32,16}_swap build the PV B-frags
//      (reg g @ quad Q = pk[2c+(Q>>1)][g&1] from quad (2Q+(g>>1))&3;
//      swap32+swap16 on (pk[2c][gr], pk[2c+1][gr]) yields regs g, g+2).
//      Pbuf DELETED: -18 LDS ops/wave-tile. PV = mfma(V^T, P^T) -> y^T;
//      l = mfma(ones, P^T). LDS 40->32 KB.
//  (b) XOR bank swizzle (both-sides, rule #21): chunk' = chunk ^ ((row>>1)&3)
//      on the DMA GLOBAL SOURCE (LDS dest stays linear) and on frag reads
//      (xk8). Spreads each 8-lane issue phase across all 32 banks.
// Keeps: R13 1-qtile/block grid 1024 + descending-size dispatch, R11
// XCD-group decode (FETCH 12 MB verified), DMA double buffer, hoisted ALiBi,
// fixed-shift softmax.
__global__ __launch_bounds__(256, 4) void k_flash(const unsigned short* __restrict__ qkb, // [2][2048][2048]
                                                  const unsigned short* __restrict__ Vt,  // [2][1024][2048]
                                                  unsigned short* __restrict__ y) {       // [2][2048][1024]
  __shared__ unsigned short Ks[2][2][64 * 32];   // [buf][half][k][d32 swz]
  __shared__ unsigned short Vs[2][2][64 * 32];   // [buf][half][d][t32 swz]
  // ---- decode: xcd = id&7; s = id>>3; group-local = s&3; qt = 31-(s>>2) ----
  int id = blockIdx.x;
  int xcd = id & 7, s = id >> 3;
  int grp = xcd + 8 * (s & 3);                   // 32 (hd,b) groups, 4 per XCD
  int qt = 31 - (s >> 2);                        // big blocks dispatched first
  int hd = grp & 15, b = grp >> 4;
  int tid = threadIdx.x;
  int w = tid >> 6, lane = tid & 63;
  int quad = lane >> 4, lq = lane & 15, lk8 = quad * 8;
  int xk8 = (quad ^ ((lq >> 1) & 3)) * 8;        // swizzled frag-read chunk
  int rs = tid >> 2;
  int csw = ((tid & 3) ^ ((tid >> 3) & 3)) * 8;  // swizzled DMA source chunk
  const size_t rowb = (size_t)b * 2048;
  const size_t vrow = ((size_t)b * 1024 + hd * 64 + rs) * 2048 + csw;
  const size_t krow = ((rowb + rs) << 11) + 1024 + hd * 64 + csw;

  float slope = exp2f(-0.5f * (float)(hd + 1));  // ALiBi, H=16 power-of-2
  const float c1 = 0.125f * LOG2E;               // 1/sqrt(64) * log2(e)
  const float c2 = slope * LOG2E;
  const float SHIFT = 16.0f;                     // fixed softmax shift (log2)

  bf16x8 ones;
#pragma unroll
  for (int i = 0; i < 8; ++i) ones[i] = (__bf16)1.0f;

  int q0 = qt * 64;
  int qr_l = q0 + w * 16 + lq;                   // this lane's q row (S^T col)
  bf16x8 qf0 = *(const bf16x8*)(qkb + ((rowb + qr_l) << 11) + hd * 64 + lk8);
  bf16x8 qf1 = *(const bf16x8*)(qkb + ((rowb + qr_l) << 11) + hd * 64 + 32 + lk8);

  // hoisted ALiBi: arg = S*c1 + base_b[s4][r] + c2*k0 ; kg_local = s4*16+quad*4+r
  float base_b[4][4];
#pragma unroll
  for (int s4 = 0; s4 < 4; ++s4)
#pragma unroll
    for (int r = 0; r < 4; ++r)
      base_b[s4][r] = c2 * (float)(s4 * 16 + quad * 4 + r - qr_l) - SHIFT;

  f32x4 o[4], o4;                                // o: y^T tiles (rows=d, cols=q)
#pragma unroll
  for (int r = 0; r < 4; ++r) o4[r] = 0.f;
#pragma unroll
  for (int jj = 0; jj < 4; ++jj)
#pragma unroll
    for (int r = 0; r < 4; ++r) o[jj][r] = 0.f;

  // ---- prologue: DMA tile 0 into buffer 0 (source pre-swizzled) ----
  GLDS16(qkb + krow,      &Ks[0][0][rs * 32 + (tid & 3) * 8]);
  GLDS16(qkb + krow + 32, &Ks[0][1][rs * 32 + (tid & 3) * 8]);
  GLDS16(Vt + vrow,       &Vs[0][0][rs * 32 + (tid & 3) * 8]);
  GLDS16(Vt + vrow + 32,  &Vs[0][1][rs * 32 + (tid & 3) * 8]);
  __syncthreads();                               // vmcnt(0) drain: tile 0 ready
  int cur = 0;

#pragma unroll 1
  for (int kt = 0; kt <= qt; ++kt) {
    int k0 = kt * 64;
    // DMA tile kt+1 into the other buffer (in flight across this tile)
    if (kt < qt) {
      size_t koff = (size_t)(k0 + 64);
      int nxt = cur ^ 1;
      GLDS16(qkb + krow + (koff << 11),      &Ks[nxt][0][rs * 32 + (tid & 3) * 8]);
      GLDS16(qkb + krow + (koff << 11) + 32, &Ks[nxt][1][rs * 32 + (tid & 3) * 8]);
      GLDS16(Vt + vrow + koff,               &Vs[nxt][0][rs * 32 + (tid & 3) * 8]);
      GLDS16(Vt + vrow + koff + 32,          &Vs[nxt][1][rs * 32 + (tid & 3) * 8]);
    }
    // K fragments (swizzled read) — used as MFMA *A* operand
    bf16x8 kc[4][2];
#pragma unroll
    for (int s4 = 0; s4 < 4; ++s4) {
      u16x8 t0 = *(const u16x8*)(&Ks[cur][0][(s4 * 16 + lq) * 32 + xk8]);
      u16x8 t1 = *(const u16x8*)(&Ks[cur][1][(s4 * 16 + lq) * 32 + xk8]);
      kc[s4][0] = __builtin_bit_cast(bf16x8, t0);
      kc[s4][1] = __builtin_bit_cast(bf16x8, t1);
    }
    // swapped QK^T: S^T[k][q], rows k = quad*4+r, cols q = lq
    f32x4 S[4];
#pragma unroll
    for (int s4 = 0; s4 < 4; ++s4) {
      f32x4 a;
#pragma unroll
      for (int r = 0; r < 4; ++r) a[r] = 0.f;
      a = __builtin_amdgcn_mfma_f32_16x16x32_bf16(kc[s4][0], qf0, a, 0, 0, 0);
      a = __builtin_amdgcn_mfma_f32_16x16x32_bf16(kc[s4][1], qf1, a, 0, 0, 0);
      S[s4] = a;
    }
    // p = exp2(score - SHIFT); masked cols -> 0
    float bk = c2 * (float)k0;
    float p[4][4];
    if (kt == qt) {
#pragma unroll
      for (int s4 = 0; s4 < 4; ++s4)
#pragma unroll
        for (int r = 0; r < 4; ++r) {
          float v = S[s4][r] * c1 + (base_b[s4][r] + bk);
          v = (k0 + s4 * 16 + quad * 4 + r <= qr_l) ? v : -1e30f;
          p[s4][r] = exp2f(v);
        }
    } else {
#pragma unroll
      for (int s4 = 0; s4 < 4; ++s4)
#pragma unroll
        for (int r = 0; r < 4; ++r) {
          float v = S[s4][r] * c1 + (base_b[s4][r] + bk);
          p[s4][r] = exp2f(v);
        }
    }
    // pack P^T to bf16 pairs: pk[s4][gr] = {k=..+2gr (lo), ..+2gr+1 (hi)}
    unsigned pk[4][2];
#pragma unroll
    for (int s4 = 0; s4 < 4; ++s4) {
      pk[s4][0] = cvt_pk(p[s4][0], p[s4][1]);
      pk[s4][1] = cvt_pk(p[s4][2], p[s4][3]);
    }
    // build PV B-frags in registers (no LDS): per chunk c (k = c*32..c*32+31)
    bf16x8 pf[2];
#pragma unroll
    for (int c = 0; c < 2; ++c) {
      unsigned a0 = pk[2 * c][0], b0 = pk[2 * c + 1][0];
      swap32(a0, b0); swap16(a0, b0);            // a0 = reg g0, b0 = reg g2
      unsigned a1 = pk[2 * c][1], b1 = pk[2 * c + 1][1];
      swap32(a1, b1); swap16(a1, b1);            // a1 = reg g1, b1 = reg g3
      u32x4 t; t[0] = a0; t[1] = a1; t[2] = b0; t[3] = b1;
      pf[c] = __builtin_bit_cast(bf16x8, t);
    }
    // l[q] = sum_k P^T[k][q] : ones as A operand
    o4 = __builtin_amdgcn_mfma_f32_16x16x32_bf16(ones, pf[0], o4, 0, 0, 0);
    o4 = __builtin_amdgcn_mfma_f32_16x16x32_bf16(ones, pf[1], o4, 0, 0, 0);
    // PV: y^T += V^T * P^T  (V^T frags from Vs, swizzled read)
#pragma unroll
    for (int jj = 0; jj < 4; ++jj) {
      u16x8 v0 = *(const u16x8*)(&Vs[cur][0][(jj * 16 + lq) * 32 + xk8]);
      u16x8 v1 = *(const u16x8*)(&Vs[cur][1][(jj * 16 + lq) * 32 + xk8]);
      bf16x8 vf0 = __builtin_bit_cast(bf16x8, v0);
      bf16x8 vf1 = __builtin_bit_cast(bf16x8, v1);
      o[jj] = __builtin_amdgcn_mfma_f32_16x16x32_bf16(vf0, pf[0], o[jj], 0, 0, 0);
      o[jj] = __builtin_amdgcn_mfma_f32_16x16x32_bf16(vf1, pf[1], o[jj], 0, 0, 0);
    }
    // switch buffers; DMA for tile kt+1 drains inside __syncthreads()
    if (kt < qt) {
      __syncthreads();
      cur ^= 1;
    }
  }
  // epilogue: lane holds q = qr_l, d = jj*16 + quad*4 + r -> packed 8B stores
  float inv = 1.0f / o4[0];                      // all o4 rows equal = l[q]
  size_t base = ((rowb + qr_l) << 10) + hd * 64 + quad * 4;
#pragma unroll
  for (int jj = 0; jj < 4; ++jj) {
    ushort4 pk4;
    pk4.x = f2b(o[jj][0] * inv);
    pk4.y = f2b(o[jj][1] * inv);
    pk4.z = f2b(o[jj][2] * inv);
    pk4.w = f2b(o[jj][3] * inv);
    *(ushort4*)(y + base + jj * 16) = pk4;
  }
}

// --- 4) out[b,t,i*64+d] = sum_j y[b,t,j*64+d] * proj_tmp[i*16+j]  (FP32 out) ---
__global__ __launch_bounds__(256) void k_proj(const unsigned short* __restrict__ yb,
                                              const float* __restrict__ pt,
                                              float* __restrict__ out) {
  __shared__ float s_pt[256];
  s_pt[threadIdx.x] = pt[threadIdx.x];
  __syncthreads();
  int g = blockIdx.x * 256 + threadIdx.x;
  int bt = g >> 6, d = g & 63;
  float yj[16];
#pragma unroll
  for (int j = 0; j < 16; ++j) yj[j] = b2f(yb[(size_t)bt * 1024 + j * 64 + d]);
#pragma unroll
  for (int i = 0; i < 16; ++i) {
    float s = 0.f;
#pragma unroll
    for (int j = 0; j < 16; ++j) s += yj[j] * s_pt[i * 16 + j];
    out[(size_t)bt * 1024 + i * 64 + d] = s;
  }
}

extern "C" void kernel_launch(void* const* d_in, const int* in_sizes, int n_in,
                              void* d_out, int out_size, void* d_ws, size_t ws_size,
                              hipStream_t stream) {
  const float* x  = (const float*)d_in[0];   // [2][2048][1024] fp32
  const float* W  = (const float*)d_in[1];   // [1024][2048] fp32
  const float* vt = (const float*)d_in[2];   // [16][16] fp32
  const float* pt = (const float*)d_in[3];   // [16][16] fp32
  float* out = (float*)d_out;                // fp32 out

  char* ws = (char*)d_ws;
  unsigned short* xb  = (unsigned short*)(ws);                 //  8 MiB, reused as y
  unsigned short* Wt  = (unsigned short*)(ws + (8u  << 20));   //  4 MiB
  unsigned short* qkb = (unsigned short*)(ws + (12u << 20));   // 16 MiB
  unsigned short* vb  = (unsigned short*)(ws + (28u << 20));   //  8 MiB
  unsigned short* Vtr = (unsigned short*)(ws + (36u << 20));   //  8 MiB
  unsigned short* yb  = xb;  // xb dead after GEMM; flash writes y there

  k_pre  <<<1536, 256, 0, stream>>>(x, vt, W, xb, vb, Wt);
  k_mid  <<<1536, 256, 0, stream>>>(xb, Wt, qkb, vb, Vtr);
  k_flash<<<1024, 256, 0, stream>>>(qkb, Vtr, yb);
  k_proj <<<1024, 256, 0, stream>>>(yb, pt, out);
}

// Round 6
// 151.198 us; speedup vs baseline: 1.1307x; 1.0142x over previous
//
#include <hip/hip_runtime.h>

typedef __attribute__((ext_vector_type(8))) __bf16 bf16x8;
typedef __attribute__((ext_vector_type(8))) unsigned short u16x8;
typedef __attribute__((ext_vector_type(4))) float f32x4;
typedef __attribute__((ext_vector_type(4))) unsigned int u32x4;

#define LOG2E 1.4426950408889634f

// async global -> LDS, 16 bytes per lane (dest must be wave-uniform base + lane*16)
#define GLDS16(gp, lp)                                                \
  __builtin_amdgcn_global_load_lds(                                   \
      (const __attribute__((address_space(1))) void*)(gp),            \
      (__attribute__((address_space(3))) void*)(lp), 16, 0, 0)

__device__ __forceinline__ unsigned short f2b(float f) {
  return __builtin_bit_cast(unsigned short, (__bf16)f);
}
__device__ __forceinline__ float b2f(unsigned short h) {
  return __uint_as_float(((unsigned)h) << 16);
}
// v_cvt_pk_bf16_f32: lo16 = bf16(a), hi16 = bf16(b)   (no builtin on gfx950)
__device__ __forceinline__ unsigned cvt_pk(float a, float b) {
  unsigned r;
  asm("v_cvt_pk_bf16_f32 %0, %1, %2" : "=v"(r) : "v"(a), "v"(b));
  return r;
}
__device__ __forceinline__ void swap32(unsigned& a, unsigned& b) {
  asm("v_permlane32_swap_b32 %0, %1" : "+v"(a), "+v"(b));
}
__device__ __forceinline__ void swap16(unsigned& a, unsigned& b) {
  asm("v_permlane16_swap_b32 %0, %1" : "+v"(a), "+v"(b));
}

// -- 1) merged launch: [0,1024) xv: xb=bf16(x), v=x@v_tmp; [1024,1536) W transpose
__global__ __launch_bounds__(256) void k_pre(const float* __restrict__ x,
                                             const float* __restrict__ vt,
                                             const float* __restrict__ W,
                                             unsigned short* __restrict__ xb,
                                             unsigned short* __restrict__ vb,
                                             unsigned short* __restrict__ Wt) {
  if (blockIdx.x < 1024) {
    __shared__ float s_vt[256];
    s_vt[threadIdx.x] = vt[threadIdx.x];
    __syncthreads();
    int g = blockIdx.x * 256 + threadIdx.x;
    int bt = g >> 6, d = g & 63;
    const float* xp = x + (size_t)bt * 1024 + d;
    float xi[16];
#pragma unroll
    for (int i = 0; i < 16; ++i) xi[i] = xp[i * 64];
#pragma unroll
    for (int i = 0; i < 16; ++i) xb[(size_t)bt * 1024 + i * 64 + d] = f2b(xi[i]);
#pragma unroll
    for (int j = 0; j < 16; ++j) {
      float s = 0.f;
#pragma unroll
      for (int i = 0; i < 16; ++i) s += xi[i] * s_vt[i * 16 + j];
      vb[(size_t)bt * 1024 + j * 64 + d] = f2b(s);
    }
  } else {
    __shared__ unsigned short tile[64][65];
    int id2 = blockIdx.x - 1024;
    int n0 = (id2 & 31) * 64;
    int k0 = (id2 >> 5) * 64;
    int tx = threadIdx.x & 63, ty = threadIdx.x >> 6;
#pragma unroll
    for (int r = 0; r < 16; ++r) {
      int kk = ty * 16 + r;
      tile[kk][tx] = f2b(W[(size_t)(k0 + kk) * 2048 + n0 + tx]);
    }
    __syncthreads();
#pragma unroll
    for (int r = 0; r < 16; ++r) {
      int nn = ty * 16 + r;
      Wt[(size_t)(n0 + nn) * 1024 + k0 + tx] = tile[tx][nn];
    }
  }
}

// -- 2) merged launch: [0,512) GEMM qk = xb @ Wt^T (m97 DMA pattern);
//                      [512,1536) vb -> Vt transpose (t-major for PV)
__global__ __launch_bounds__(256) void k_mid(const unsigned short* __restrict__ A,
                                             const unsigned short* __restrict__ Bt,
                                             unsigned short* __restrict__ C,
                                             const unsigned short* __restrict__ vb,
                                             unsigned short* __restrict__ Vt) {
  if (blockIdx.x < 512) {
    __shared__ unsigned short As[128 * 32];
    __shared__ unsigned short Bs[128 * 32];
    const int K = 1024;
    int m0 = (blockIdx.x & 31) * 128;
    int n0 = (blockIdx.x >> 5) * 128;
    int tid = threadIdx.x;
    int w = tid >> 6, lane = tid & 63;
    int lq = lane & 15, lk8 = (lane >> 4) * 8;
    int wr = (w >> 1) * 64, wc = (w & 1) * 64;
    f32x4 acc[4][4];
#pragma unroll
    for (int i = 0; i < 4; ++i)
#pragma unroll
      for (int j = 0; j < 4; ++j)
#pragma unroll
        for (int r = 0; r < 4; ++r) acc[i][j][r] = 0.f;

    for (int kk = 0; kk < K; kk += 32) {
      __syncthreads();
#pragma unroll
      for (int i = 0; i < 2; ++i) {
        int c = tid + 256 * i;
        int row = c >> 2, col = (c & 3) * 8;
        GLDS16(A + (size_t)(m0 + row) * K + kk + col, As + c * 8);
        GLDS16(Bt + (size_t)(n0 + row) * K + kk + col, Bs + c * 8);
      }
      __syncthreads();
      bf16x8 af[4], bf[4];
#pragma unroll
      for (int i = 0; i < 4; ++i) af[i] = *(const bf16x8*)(As + (wr + i * 16 + lq) * 32 + lk8);
#pragma unroll
      for (int j = 0; j < 4; ++j) bf[j] = *(const bf16x8*)(Bs + (wc + j * 16 + lq) * 32 + lk8);
#pragma unroll
      for (int i = 0; i < 4; ++i)
#pragma unroll
        for (int j = 0; j < 4; ++j)
          acc[i][j] = __builtin_amdgcn_mfma_f32_16x16x32_bf16(af[i], bf[j], acc[i][j], 0, 0, 0);
    }
#pragma unroll
    for (int i = 0; i < 4; ++i)
#pragma unroll
      for (int j = 0; j < 4; ++j)
#pragma unroll
        for (int r = 0; r < 4; ++r) {
          int m = m0 + wr + i * 16 + (lane >> 4) * 4 + r;
          int n = n0 + wc + j * 16 + lq;
          C[(size_t)m * 2048 + n] = f2b(acc[i][j][r]);
        }
  } else {
    __shared__ unsigned short tile[64][65];
    int id2 = blockIdx.x - 512;
    int t0 = (id2 & 31) * 64;
    int c0 = ((id2 >> 5) & 15) * 64;
    int b = id2 >> 9;
    int tx = threadIdx.x & 63, ty = threadIdx.x >> 6;
#pragma unroll
    for (int r = 0; r < 16; ++r) {
      int tt = ty * 16 + r;
      tile[tt][tx] = vb[((size_t)b * 2048 + t0 + tt) * 1024 + c0 + tx];
    }
    __syncthreads();
#pragma unroll
    for (int r = 0; r < 16; ++r) {
      int cc = ty * 16 + r;
      Vt[((size_t)b * 1024 + c0 + cc) * 2048 + t0 + tx] = tile[tx][cc];
    }
  }
}

// ---------------- 3) causal flash attention with ALiBi ----------------------
// R15: K-SPLIT WAVES. R14 halved LDS ops by deleting Pbuf; the remaining
// LDS-read traffic was 4x-redundant (all 4 waves read identical K/V frags).
// New decomposition: wave w owns (q-half w>>1 [32 q], k-half w&1 [32 k of
// each tile]). Per wave-tile: 4 K + 4 V ds_read_b128 (HALF of R14's 8+8);
// MFMA/softmax/pack counts unchanged (q*k product fixed). Fixed-shift
// softmax is linear in k => k-halves combine by ONE cross-wave add at
// kernel end (LDS round-trip through dead Ks/Vs). T5 setprio around MFMA
// clusters (attn-positive, m191). Keeps: swapped QK^T + in-register
// cvt_pk/permlane P-transpose, XOR bank swizzle (both-sides), 1-qtile/block
// grid 1024 descending, XCD-group decode, DMA double buffer, hoisted ALiBi.
__global__ __launch_bounds__(256, 4) void k_flash(const unsigned short* __restrict__ qkb, // [2][2048][2048]
                                                  const unsigned short* __restrict__ Vt,  // [2][1024][2048]
                                                  unsigned short* __restrict__ y) {       // [2][2048][1024]
  __shared__ unsigned short Ks[2][2][64 * 32];   // [buf][half][k][d32 swz]
  __shared__ unsigned short Vs[2][2][64 * 32];   // [buf][half][d][t32 swz]
  // ---- decode: xcd = id&7; s = id>>3; group-local = s&3; qt = 31-(s>>2) ----
  int id = blockIdx.x;
  int xcd = id & 7, s = id >> 3;
  int grp = xcd + 8 * (s & 3);                   // 32 (hd,b) groups, 4 per XCD
  int qt = 31 - (s >> 2);                        // big blocks dispatched first
  int hd = grp & 15, b = grp >> 4;
  int tid = threadIdx.x;
  int w = tid >> 6, lane = tid & 63;
  int quad = lane >> 4, lq = lane & 15, lk8 = quad * 8;
  int xk8 = (quad ^ ((lq >> 1) & 3)) * 8;        // swizzled frag-read chunk
  int qh = w >> 1, kh = w & 1;                   // q-half / k-half of this wave
  int rs = tid >> 2;
  int csw = ((tid & 3) ^ ((tid >> 3) & 3)) * 8;  // swizzled DMA source chunk
  const size_t rowb = (size_t)b * 2048;
  const size_t vrow = ((size_t)b * 1024 + hd * 64 + rs) * 2048 + csw;
  const size_t krow = ((rowb + rs) << 11) + 1024 + hd * 64 + csw;

  float slope = exp2f(-0.5f * (float)(hd + 1));  // ALiBi, H=16 power-of-2
  const float c1 = 0.125f * LOG2E;               // 1/sqrt(64) * log2(e)
  const float c2 = slope * LOG2E;
  const float c16 = 16.0f * c2;
  const float SHIFT = 16.0f;                     // fixed softmax shift (log2)

  bf16x8 ones;
#pragma unroll
  for (int i = 0; i < 8; ++i) ones[i] = (__bf16)1.0f;

  int q0 = qt * 64;
  int qrow = q0 + qh * 32;                       // wave's q-base
  bf16x8 qf[2][2];                               // [q-subtile][d-half]
#pragma unroll
  for (int qs2 = 0; qs2 < 2; ++qs2) {
    int qg = qrow + qs2 * 16 + lq;
    qf[qs2][0] = *(const bf16x8*)(qkb + ((rowb + qg) << 11) + hd * 64 + lk8);
    qf[qs2][1] = *(const bf16x8*)(qkb + ((rowb + qg) << 11) + hd * 64 + 32 + lk8);
  }
  // ALiBi: arg = S*c1 + base0[r] + c2*k0 + c16*(ks2 - qs2)
  // (k_local = kh*32 + ks2*16 + quad*4 + r ; q = qrow + qs2*16 + lq)
  int kq0 = kh * 32 + quad * 4 - qrow - lq;      // per-lane k-q offset (ks2=qs2=0,r=0)
  float base0[4];
#pragma unroll
  for (int r = 0; r < 4; ++r) base0[r] = c2 * (float)(kq0 + r) - SHIFT;

  f32x4 o[4][2];                                 // [d-subtile][q-subtile], partial over k-half
  f32x4 o4[2];
#pragma unroll
  for (int r = 0; r < 4; ++r) { o4[0][r] = 0.f; o4[1][r] = 0.f; }
#pragma unroll
  for (int jj = 0; jj < 4; ++jj)
#pragma unroll
    for (int qs2 = 0; qs2 < 2; ++qs2)
#pragma unroll
      for (int r = 0; r < 4; ++r) o[jj][qs2][r] = 0.f;

  // ---- prologue: DMA tile 0 into buffer 0 (source pre-swizzled) ----
  GLDS16(qkb + krow,      &Ks[0][0][rs * 32 + (tid & 3) * 8]);
  GLDS16(qkb + krow + 32, &Ks[0][1][rs * 32 + (tid & 3) * 8]);
  GLDS16(Vt + vrow,       &Vs[0][0][rs * 32 + (tid & 3) * 8]);
  GLDS16(Vt + vrow + 32,  &Vs[0][1][rs * 32 + (tid & 3) * 8]);
  __syncthreads();                               // vmcnt(0) drain: tile 0 ready
  int cur = 0;

#pragma unroll 1
  for (int kt = 0; kt <= qt; ++kt) {
    int k0 = kt * 64;
    // DMA tile kt+1 into the other buffer (in flight across this tile)
    if (kt < qt) {
      size_t koff = (size_t)(k0 + 64);
      int nxt = cur ^ 1;
      GLDS16(qkb + krow + (koff << 11),      &Ks[nxt][0][rs * 32 + (tid & 3) * 8]);
      GLDS16(qkb + krow + (koff << 11) + 32, &Ks[nxt][1][rs * 32 + (tid & 3) * 8]);
      GLDS16(Vt + vrow + koff,               &Vs[nxt][0][rs * 32 + (tid & 3) * 8]);
      GLDS16(Vt + vrow + koff + 32,          &Vs[nxt][1][rs * 32 + (tid & 3) * 8]);
    }
    // K fragments: only this wave's k-half (4 reads)
    bf16x8 kc[2][2];                             // [k-subtile][d-half]
#pragma unroll
    for (int ks2 = 0; ks2 < 2; ++ks2) {
      u16x8 t0 = *(const u16x8*)(&Ks[cur][0][(kh * 32 + ks2 * 16 + lq) * 32 + xk8]);
      u16x8 t1 = *(const u16x8*)(&Ks[cur][1][(kh * 32 + ks2 * 16 + lq) * 32 + xk8]);
      kc[ks2][0] = __builtin_bit_cast(bf16x8, t0);
      kc[ks2][1] = __builtin_bit_cast(bf16x8, t1);
    }
    // swapped QK^T: S^T[k][q] per (ks2, qs2)
    __builtin_amdgcn_s_setprio(1);
    f32x4 S[2][2];
#pragma unroll
    for (int ks2 = 0; ks2 < 2; ++ks2)
#pragma unroll
      for (int qs2 = 0; qs2 < 2; ++qs2) {
        f32x4 a;
#pragma unroll
        for (int r = 0; r < 4; ++r) a[r] = 0.f;
        a = __builtin_amdgcn_mfma_f32_16x16x32_bf16(kc[ks2][0], qf[qs2][0], a, 0, 0, 0);
        a = __builtin_amdgcn_mfma_f32_16x16x32_bf16(kc[ks2][1], qf[qs2][1], a, 0, 0, 0);
        S[ks2][qs2] = a;
      }
    __builtin_amdgcn_s_setprio(0);
    // p = exp2(score - SHIFT); masked cols -> 0
    float bk = c2 * (float)k0;
    float p[2][2][4];
    if (kt == qt) {
#pragma unroll
      for (int ks2 = 0; ks2 < 2; ++ks2)
#pragma unroll
        for (int qs2 = 0; qs2 < 2; ++qs2)
#pragma unroll
          for (int r = 0; r < 4; ++r) {
            float v = S[ks2][qs2][r] * c1 + (base0[r] + bk + c16 * (float)(ks2 - qs2));
            v = (k0 + kq0 + (ks2 - qs2) * 16 + r <= 0) ? v : -1e30f;
            p[ks2][qs2][r] = exp2f(v);
          }
    } else {
#pragma unroll
      for (int ks2 = 0; ks2 < 2; ++ks2)
#pragma unroll
        for (int qs2 = 0; qs2 < 2; ++qs2)
#pragma unroll
          for (int r = 0; r < 4; ++r) {
            float v = S[ks2][qs2][r] * c1 + (base0[r] + bk + c16 * (float)(ks2 - qs2));
            p[ks2][qs2][r] = exp2f(v);
          }
    }
    // pack P^T to bf16 pairs, then build PV B-frags in registers
    unsigned pk[2][2][2];                        // [ks2][qs2][gr]
#pragma unroll
    for (int ks2 = 0; ks2 < 2; ++ks2)
#pragma unroll
      for (int qs2 = 0; qs2 < 2; ++qs2) {
        pk[ks2][qs2][0] = cvt_pk(p[ks2][qs2][0], p[ks2][qs2][1]);
        pk[ks2][qs2][1] = cvt_pk(p[ks2][qs2][2], p[ks2][qs2][3]);
      }
    bf16x8 pf[2];                                // [q-subtile], K=32 = wave's k-half
#pragma unroll
    for (int qs2 = 0; qs2 < 2; ++qs2) {
      unsigned a0 = pk[0][qs2][0], b0 = pk[1][qs2][0];
      swap32(a0, b0); swap16(a0, b0);
      unsigned a1 = pk[0][qs2][1], b1 = pk[1][qs2][1];
      swap32(a1, b1); swap16(a1, b1);
      u32x4 t; t[0] = a0; t[1] = a1; t[2] = b0; t[3] = b1;
      pf[qs2] = __builtin_bit_cast(bf16x8, t);
    }
    // l[q] partial + PV partial (V frags: only this wave's k-half, 4 reads)
    __builtin_amdgcn_s_setprio(1);
    o4[0] = __builtin_amdgcn_mfma_f32_16x16x32_bf16(ones, pf[0], o4[0], 0, 0, 0);
    o4[1] = __builtin_amdgcn_mfma_f32_16x16x32_bf16(ones, pf[1], o4[1], 0, 0, 0);
#pragma unroll
    for (int jj = 0; jj < 4; ++jj) {
      u16x8 v0 = *(const u16x8*)(&Vs[cur][kh][(jj * 16 + lq) * 32 + xk8]);
      bf16x8 vf = __builtin_bit_cast(bf16x8, v0);
      o[jj][0] = __builtin_amdgcn_mfma_f32_16x16x32_bf16(vf, pf[0], o[jj][0], 0, 0, 0);
      o[jj][1] = __builtin_amdgcn_mfma_f32_16x16x32_bf16(vf, pf[1], o[jj][1], 0, 0, 0);
    }
    __builtin_amdgcn_s_setprio(0);
    // switch buffers; DMA for tile kt+1 drains inside __syncthreads()
    if (kt < qt) {
      __syncthreads();
      cur ^= 1;
    }
  }

  // ---- cross-wave k-half reduction through LDS (Ks/Vs are dead) ----
  __syncthreads();                               // all tile reads done
  float* red0 = (float*)&Ks[0][0][0];            // 16 KB: qh=0
  float* red1 = (float*)&Vs[0][0][0];            // 16 KB: qh=1
  float* red = (qh ? red1 : red0) + lane * 36;
  if (kh == 1) {
#pragma unroll
    for (int jj = 0; jj < 4; ++jj)
#pragma unroll
      for (int qs2 = 0; qs2 < 2; ++qs2)
#pragma unroll
        for (int r = 0; r < 4; ++r) red[(jj * 2 + qs2) * 4 + r] = o[jj][qs2][r];
    red[32] = o4[0][0];
    red[33] = o4[1][0];
  }
  __syncthreads();
  if (kh == 0) {
#pragma unroll
    for (int jj = 0; jj < 4; ++jj)
#pragma unroll
      for (int qs2 = 0; qs2 < 2; ++qs2)
#pragma unroll
        for (int r = 0; r < 4; ++r) o[jj][qs2][r] += red[(jj * 2 + qs2) * 4 + r];
    float inv0 = 1.0f / (o4[0][0] + red[32]);
    float inv1 = 1.0f / (o4[1][0] + red[33]);
    // epilogue: lane holds q = qrow + qs2*16 + lq, d = jj*16 + quad*4 + r
#pragma unroll
    for (int qs2 = 0; qs2 < 2; ++qs2) {
      float inv = qs2 ? inv1 : inv0;
      size_t base = ((rowb + qrow + qs2 * 16 + lq) << 10) + hd * 64 + quad * 4;
#pragma unroll
      for (int jj = 0; jj < 4; ++jj) {
        ushort4 pk4;
        pk4.x = f2b(o[jj][qs2][0] * inv);
        pk4.y = f2b(o[jj][qs2][1] * inv);
        pk4.z = f2b(o[jj][qs2][2] * inv);
        pk4.w = f2b(o[jj][qs2][3] * inv);
        *(ushort4*)(y + base + jj * 16) = pk4;
      }
    }
  }
}

// --- 4) out[b,t,i*64+d] = sum_j y[b,t,j*64+d] * proj_tmp[i*16+j]  (FP32 out) ---
__global__ __launch_bounds__(256) void k_proj(const unsigned short* __restrict__ yb,
                                              const float* __restrict__ pt,
                                              float* __restrict__ out) {
  __shared__ float s_pt[256];
  s_pt[threadIdx.x] = pt[threadIdx.x];
  __syncthreads();
  int g = blockIdx.x * 256 + threadIdx.x;
  int bt = g >> 6, d = g & 63;
  float yj[16];
#pragma unroll
  for (int j = 0; j < 16; ++j) yj[j] = b2f(yb[(size_t)bt * 1024 + j * 64 + d]);
#pragma unroll
  for (int i = 0; i < 16; ++i) {
    float s = 0.f;
#pragma unroll
    for (int j = 0; j < 16; ++j) s += yj[j] * s_pt[i * 16 + j];
    out[(size_t)bt * 1024 + i * 64 + d] = s;
  }
}

extern "C" void kernel_launch(void* const* d_in, const int* in_sizes, int n_in,
                              void* d_out, int out_size, void* d_ws, size_t ws_size,
                              hipStream_t stream) {
  const float* x  = (const float*)d_in[0];   // [2][2048][1024] fp32
  const float* W  = (const float*)d_in[1];   // [1024][2048] fp32
  const float* vt = (const float*)d_in[2];   // [16][16] fp32
  const float* pt = (const float*)d_in[3];   // [16][16] fp32
  float* out = (float*)d_out;                // fp32 out

  char* ws = (char*)d_ws;
  unsigned short* xb  = (unsigned short*)(ws);                 //  8 MiB, reused as y
  unsigned short* Wt  = (unsigned short*)(ws + (8u  << 20));   //  4 MiB
  unsigned short* qkb = (unsigned short*)(ws + (12u << 20));   // 16 MiB
  unsigned short* vb  = (unsigned short*)(ws + (28u << 20));   //  8 MiB
  unsigned short* Vtr = (unsigned short*)(ws + (36u << 20));   //  8 MiB
  unsigned short* yb  = xb;  // xb dead after GEMM; flash writes y there

  k_pre  <<<1536, 256, 0, stream>>>(x, vt, W, xb, vb, Wt);
  k_mid  <<<1536, 256, 0, stream>>>(xb, Wt, qkb, vb, Vtr);
  k_flash<<<1024, 256, 0, stream>>>(qkb, Vtr, yb);
  k_proj <<<1024, 256, 0, stream>>>(yb, pt, out);
}